// Round 1
// baseline (67.822 us; speedup 1.0000x reference)
//
#include <hip/hip_runtime.h>

constexpr int GRID_SZ = 5;
constexpr int N_CTRL  = 25;
constexpr int IMG_H   = 256;
constexpr int IMG_W   = 192;
constexpr int BATCH   = 64;
constexpr int BCHUNK  = 8;   // batches per thread
constexpr float RBF_SCALE = 10.0f;
constexpr float OFF_SCALE = 0.3f;

__global__ __launch_bounds__(256, 4) void tps_warp_kernel(
    const float* __restrict__ cloth,   // (64,3,256,192)
    const float* __restrict__ theta,   // (64,50)
    float* __restrict__ out)           // (64,3,256,192)
{
    __shared__ float s_off[BCHUNK * N_CTRL * 2];

    const int b0 = blockIdx.y * BCHUNK;
    // stage this chunk's offsets (theta * 0.3) into LDS: 400 floats
    for (int i = threadIdx.x; i < BCHUNK * N_CTRL * 2; i += 256)
        s_off[i] = theta[b0 * (N_CTRL * 2) + i] * OFF_SCALE;
    __syncthreads();

    const int pix = blockIdx.x * 256 + threadIdx.x;   // H*W = 49152, divisible by 256
    const int hh = pix / IMG_W;
    const int ww = pix - hh * IMG_W;

    const float mx = -1.0f + (2.0f / (IMG_W - 1)) * (float)ww;
    const float my = -1.0f + (2.0f / (IMG_H - 1)) * (float)hh;

    // batch-independent RBF basis, 25 exps per pixel
    float wgt[N_CTRL];
#pragma unroll
    for (int n = 0; n < N_CTRL; ++n) {
        const float sx = -0.9f + 0.45f * (float)(n % GRID_SZ);  // x = column index
        const float sy = -0.9f + 0.45f * (float)(n / GRID_SZ);  // y = row index
        const float dx = mx - sx;
        const float dy = my - sy;
        wgt[n] = __expf(-(dx * dx + dy * dy) * RBF_SCALE);
    }

#pragma unroll
    for (int bi = 0; bi < BCHUNK; ++bi) {
        const int b = b0 + bi;

        float ox = 0.0f, oy = 0.0f;
#pragma unroll
        for (int n = 0; n < N_CTRL; ++n) {
            // wave-uniform LDS reads -> broadcast, conflict-free
            ox = fmaf(s_off[(bi * N_CTRL + n) * 2 + 0], wgt[n], ox);
            oy = fmaf(s_off[(bi * N_CTRL + n) * 2 + 1], wgt[n], oy);
        }

        float gx = mx + ox;
        float gy = my + oy;
        gx = fminf(fmaxf(gx, -1.0f), 1.0f);
        gy = fminf(fmaxf(gy, -1.0f), 1.0f);

        const float x = (gx + 1.0f) * 0.5f * (float)(IMG_W - 1);
        const float y = (gy + 1.0f) * 0.5f * (float)(IMG_H - 1);
        const float x0f = floorf(x);
        const float y0f = floorf(y);
        const float wx = x - x0f;
        const float wy = y - y0f;

        int x0 = (int)x0f;
        int y0 = (int)y0f;
        int x1 = x0 + 1;
        int y1 = y0 + 1;
        x0 = min(max(x0, 0), IMG_W - 1);
        x1 = min(max(x1, 0), IMG_W - 1);
        y0 = min(max(y0, 0), IMG_H - 1);
        y1 = min(max(y1, 0), IMG_H - 1);

        const float wa = (1.0f - wx) * (1.0f - wy);
        const float wb = wx * (1.0f - wy);
        const float wc = (1.0f - wx) * wy;
        const float wd = wx * wy;

        const float* img = cloth + (size_t)b * 3 * IMG_H * IMG_W;
        float*       op  = out   + (size_t)b * 3 * IMG_H * IMG_W + pix;

        const int ia = y0 * IMG_W + x0;
        const int ib = y0 * IMG_W + x1;
        const int ic = y1 * IMG_W + x0;
        const int id = y1 * IMG_W + x1;

#pragma unroll
        for (int c = 0; c < 3; ++c) {
            const float* pc = img + c * (IMG_H * IMG_W);
            const float Ia = pc[ia];
            const float Ib = pc[ib];
            const float Ic = pc[ic];
            const float Id = pc[id];
            op[c * (IMG_H * IMG_W)] = wa * Ia + wb * Ib + wc * Ic + wd * Id;
        }
    }
}

extern "C" void kernel_launch(void* const* d_in, const int* in_sizes, int n_in,
                              void* d_out, int out_size, void* d_ws, size_t ws_size,
                              hipStream_t stream) {
    const float* cloth = (const float*)d_in[0];
    const float* theta = (const float*)d_in[1];
    float* out = (float*)d_out;

    dim3 grid((IMG_H * IMG_W) / 256, BATCH / BCHUNK);
    dim3 block(256);
    tps_warp_kernel<<<grid, block, 0, stream>>>(cloth, theta, out);
}

// Round 2
// 49.568 us; speedup vs baseline: 1.3683x; 1.3683x over previous
//
#include <hip/hip_runtime.h>

constexpr int GRID_SZ = 5;
constexpr int N_CTRL  = 25;
constexpr int IMG_H   = 256;
constexpr int IMG_W   = 192;
constexpr int BATCH   = 64;
constexpr int BCHUNK  = 2;    // batches per thread
constexpr int PIX_BLOCKS = (IMG_H * IMG_W) / 256;   // 192
constexpr int NWG = PIX_BLOCKS * (BATCH / BCHUNK);  // 6144, divisible by 8
constexpr float RBF_SCALE = 10.0f;
constexpr float OFF_SCALE = 0.3f;

__global__ __launch_bounds__(256) void tps_warp_kernel(
    const float* __restrict__ cloth,   // (64,3,256,192)
    const float* __restrict__ theta,   // (64,50)
    float* __restrict__ out)           // (64,3,256,192)
{
    __shared__ float s_off[BCHUNK * N_CTRL * 2];

    // ---- XCD-aware bijective swizzle: each XCD gets a contiguous wgid range
    // (contiguous range = few whole images -> fits its private 4 MiB L2)
    const int flat = blockIdx.y * gridDim.x + blockIdx.x;
    const int wg   = (flat & 7) * (NWG / 8) + (flat >> 3);
    const int pb   = wg % PIX_BLOCKS;        // pixel-block
    const int bc   = wg / PIX_BLOCKS;        // batch-chunk
    const int b0   = bc * BCHUNK;

    // stage this chunk's offsets (theta * 0.3) into LDS: 100 floats
    for (int i = threadIdx.x; i < BCHUNK * N_CTRL * 2; i += 256)
        s_off[i] = theta[b0 * (N_CTRL * 2) + i] * OFF_SCALE;
    __syncthreads();

    const int pix = pb * 256 + threadIdx.x;
    const int hh = pix / IMG_W;
    const int ww = pix - hh * IMG_W;

    const float mx = -1.0f + (2.0f / (IMG_W - 1)) * (float)ww;
    const float my = -1.0f + (2.0f / (IMG_H - 1)) * (float)hh;

    // batch-independent RBF basis, 25 exps per pixel
    float wgt[N_CTRL];
#pragma unroll
    for (int n = 0; n < N_CTRL; ++n) {
        const float sx = -0.9f + 0.45f * (float)(n % GRID_SZ);
        const float sy = -0.9f + 0.45f * (float)(n / GRID_SZ);
        const float dx = mx - sx;
        const float dy = my - sy;
        wgt[n] = __expf(-(dx * dx + dy * dy) * RBF_SCALE);
    }

    // ---- phase 1: per-batch sample coordinates + weights (no loads yet)
    float wa[BCHUNK], wb[BCHUNK], wc[BCHUNK], wd[BCHUNK];
    int ia[BCHUNK], ibx[BCHUNK], ic[BCHUNK], idx[BCHUNK];
#pragma unroll
    for (int bi = 0; bi < BCHUNK; ++bi) {
        float ox = 0.0f, oy = 0.0f;
#pragma unroll
        for (int n = 0; n < N_CTRL; ++n) {
            ox = fmaf(s_off[(bi * N_CTRL + n) * 2 + 0], wgt[n], ox);
            oy = fmaf(s_off[(bi * N_CTRL + n) * 2 + 1], wgt[n], oy);
        }
        float gx = fminf(fmaxf(mx + ox, -1.0f), 1.0f);
        float gy = fminf(fmaxf(my + oy, -1.0f), 1.0f);

        const float x = (gx + 1.0f) * 0.5f * (float)(IMG_W - 1);
        const float y = (gy + 1.0f) * 0.5f * (float)(IMG_H - 1);
        const float x0f = floorf(x);
        const float y0f = floorf(y);
        const float wx = x - x0f;
        const float wy = y - y0f;

        int x0 = (int)x0f, y0 = (int)y0f;
        int x1 = x0 + 1,   y1 = y0 + 1;
        x0 = min(max(x0, 0), IMG_W - 1);
        x1 = min(max(x1, 0), IMG_W - 1);
        y0 = min(max(y0, 0), IMG_H - 1);
        y1 = min(max(y1, 0), IMG_H - 1);

        wa[bi] = (1.0f - wx) * (1.0f - wy);
        wb[bi] = wx * (1.0f - wy);
        wc[bi] = (1.0f - wx) * wy;
        wd[bi] = wx * wy;
        ia[bi]  = y0 * IMG_W + x0;
        ibx[bi] = y0 * IMG_W + x1;
        ic[bi]  = y1 * IMG_W + x0;
        idx[bi] = y1 * IMG_W + x1;
    }

    // ---- phase 2: issue ALL 24 gather loads before consuming any (MLP)
    float va[BCHUNK][3], vb[BCHUNK][3], vc[BCHUNK][3], vd[BCHUNK][3];
#pragma unroll
    for (int bi = 0; bi < BCHUNK; ++bi) {
        const float* img = cloth + (size_t)(b0 + bi) * 3 * IMG_H * IMG_W;
#pragma unroll
        for (int c = 0; c < 3; ++c) {
            const float* pc = img + c * (IMG_H * IMG_W);
            va[bi][c] = pc[ia[bi]];
            vb[bi][c] = pc[ibx[bi]];
            vc[bi][c] = pc[ic[bi]];
            vd[bi][c] = pc[idx[bi]];
        }
    }

    // ---- phase 3: blend + store (coalesced across threads)
#pragma unroll
    for (int bi = 0; bi < BCHUNK; ++bi) {
        float* op = out + (size_t)(b0 + bi) * 3 * IMG_H * IMG_W + pix;
#pragma unroll
        for (int c = 0; c < 3; ++c) {
            op[c * (IMG_H * IMG_W)] =
                wa[bi] * va[bi][c] + wb[bi] * vb[bi][c] +
                wc[bi] * vc[bi][c] + wd[bi] * vd[bi][c];
        }
    }
}

extern "C" void kernel_launch(void* const* d_in, const int* in_sizes, int n_in,
                              void* d_out, int out_size, void* d_ws, size_t ws_size,
                              hipStream_t stream) {
    const float* cloth = (const float*)d_in[0];
    const float* theta = (const float*)d_in[1];
    float* out = (float*)d_out;

    dim3 grid(PIX_BLOCKS, BATCH / BCHUNK);
    dim3 block(256);
    tps_warp_kernel<<<grid, block, 0, stream>>>(cloth, theta, out);
}

// Round 3
// 47.209 us; speedup vs baseline: 1.4366x; 1.0500x over previous
//
#include <hip/hip_runtime.h>

constexpr int GRID_SZ = 5;
constexpr int N_CTRL  = 25;
constexpr int IMG_H   = 256;
constexpr int IMG_W   = 192;
constexpr int BATCH   = 64;
constexpr int BCHUNK  = 8;    // batches per block (looped, pipelined)
constexpr int PLANE   = IMG_H * IMG_W;
constexpr int PIX_BLOCKS = PLANE / 256;             // 192
constexpr int NWG = PIX_BLOCKS * (BATCH / BCHUNK);  // 1536, divisible by 8
constexpr float RBF_SCALE = 10.0f;
constexpr float OFF_SCALE = 0.3f;

struct Samp { float wa, wb, wc, wd; int ia, ib, ic, id; };

__device__ __forceinline__ Samp mk_samp(float mx, float my,
                                        const float* __restrict__ s_off,
                                        const float* __restrict__ wgt, int bi) {
    float ox = 0.0f, oy = 0.0f;
#pragma unroll
    for (int n = 0; n < N_CTRL; ++n) {
        ox = fmaf(s_off[(bi * N_CTRL + n) * 2 + 0], wgt[n], ox);
        oy = fmaf(s_off[(bi * N_CTRL + n) * 2 + 1], wgt[n], oy);
    }
    float gx = fminf(fmaxf(mx + ox, -1.0f), 1.0f);
    float gy = fminf(fmaxf(my + oy, -1.0f), 1.0f);

    const float x = (gx + 1.0f) * 0.5f * (float)(IMG_W - 1);
    const float y = (gy + 1.0f) * 0.5f * (float)(IMG_H - 1);
    const float x0f = floorf(x);
    const float y0f = floorf(y);
    const float wx = x - x0f;
    const float wy = y - y0f;

    int x0 = (int)x0f, y0 = (int)y0f;
    int x1 = min(x0 + 1, IMG_W - 1);
    int y1 = min(y0 + 1, IMG_H - 1);
    x0 = min(max(x0, 0), IMG_W - 1);
    y0 = min(max(y0, 0), IMG_H - 1);

    Samp s;
    s.wa = (1.0f - wx) * (1.0f - wy);
    s.wb = wx * (1.0f - wy);
    s.wc = (1.0f - wx) * wy;
    s.wd = wx * wy;
    s.ia = y0 * IMG_W + x0;
    s.ib = y0 * IMG_W + x1;
    s.ic = y1 * IMG_W + x0;
    s.id = y1 * IMG_W + x1;
    return s;
}

__device__ __forceinline__ void ld12(const float* __restrict__ img,
                                     const Samp& s, float v[12]) {
#pragma unroll
    for (int c = 0; c < 3; ++c) {
        const float* pc = img + c * PLANE;
        v[c * 4 + 0] = pc[s.ia];
        v[c * 4 + 1] = pc[s.ib];
        v[c * 4 + 2] = pc[s.ic];
        v[c * 4 + 3] = pc[s.id];
    }
}

__device__ __forceinline__ void blend_store(float* __restrict__ op,
                                            const Samp& s, const float v[12]) {
#pragma unroll
    for (int c = 0; c < 3; ++c) {
        float r = s.wa * v[c * 4 + 0] + s.wb * v[c * 4 + 1] +
                  s.wc * v[c * 4 + 2] + s.wd * v[c * 4 + 3];
        __builtin_nontemporal_store(r, op + c * PLANE);   // output never re-read
    }
}

__global__ __launch_bounds__(256) void tps_warp_kernel(
    const float* __restrict__ cloth,   // (64,3,256,192)
    const float* __restrict__ theta,   // (64,50)
    float* __restrict__ out)           // (64,3,256,192)
{
    __shared__ float s_off[BCHUNK * N_CTRL * 2];   // 400 floats

    // XCD swizzle: flat&7 = XCD id -> each XCD owns ONE whole batch-chunk
    // (8 images = 4.7 MB ~ its private L2); pixel-blocks advance together.
    const int flat = blockIdx.x;
    const int bc   = flat & 7;
    const int pb   = flat >> 3;
    const int b0   = bc * BCHUNK;

    for (int i = threadIdx.x; i < BCHUNK * N_CTRL * 2; i += 256)
        s_off[i] = theta[b0 * (N_CTRL * 2) + i] * OFF_SCALE;
    __syncthreads();

    const int pix = pb * 256 + threadIdx.x;
    const int hh = pix / IMG_W;
    const int ww = pix - hh * IMG_W;
    const float mx = -1.0f + (2.0f / (IMG_W - 1)) * (float)ww;
    const float my = -1.0f + (2.0f / (IMG_H - 1)) * (float)hh;

    // separable RBF basis: 10 exps + 25 muls (once for all 8 batches)
    float ex[GRID_SZ], ey[GRID_SZ];
#pragma unroll
    for (int k = 0; k < GRID_SZ; ++k) {
        const float c = -0.9f + 0.45f * (float)k;
        const float dx = mx - c;
        const float dy = my - c;
        ex[k] = __expf(-dx * dx * RBF_SCALE);
        ey[k] = __expf(-dy * dy * RBF_SCALE);
    }
    float wgt[N_CTRL];
#pragma unroll
    for (int n = 0; n < N_CTRL; ++n)
        wgt[n] = ex[n % GRID_SZ] * ey[n / GRID_SZ];

    const size_t img_stride = (size_t)3 * PLANE;
    const float* img0 = cloth + (size_t)b0 * img_stride;
    float*       out0 = out   + (size_t)b0 * img_stride + pix;

    // ---- 1-deep pipelined batch loop: loads for bi+1 in flight while blending bi
    Samp  s[2];
    float v[2][12];
    s[0] = mk_samp(mx, my, s_off, wgt, 0);
    ld12(img0, s[0], v[0]);

#pragma unroll
    for (int bi = 0; bi < BCHUNK; ++bi) {
        const int cur = bi & 1;        // compile-time after full unroll
        const int nxt = cur ^ 1;
        if (bi + 1 < BCHUNK) {
            s[nxt] = mk_samp(mx, my, s_off, wgt, bi + 1);
            ld12(img0 + (size_t)(bi + 1) * img_stride, s[nxt], v[nxt]);
        }
        blend_store(out0 + (size_t)bi * img_stride, s[cur], v[cur]);
    }
}

extern "C" void kernel_launch(void* const* d_in, const int* in_sizes, int n_in,
                              void* d_out, int out_size, void* d_ws, size_t ws_size,
                              hipStream_t stream) {
    const float* cloth = (const float*)d_in[0];
    const float* theta = (const float*)d_in[1];
    float* out = (float*)d_out;

    tps_warp_kernel<<<dim3(NWG), dim3(256), 0, stream>>>(cloth, theta, out);
}